// Round 3
// baseline (138.172 us; speedup 1.0000x reference)
//
#include <hip/hip_runtime.h>

// Problem constants: B=16, C=512, H=W=14 (HW=196), D=8000.
#define B_DIM 16
#define C_DIM 512
#define HW_DIM 196
#define D_DIM 8000

#define KT 28            // 196 = 7*28 -> no K guards
#define IT 128           // i-tile (c1)
#define JT 64            // j-tile (c2)
#define PAD 4            // pad keeps rows 16B-aligned: (128+4)*4=528, (64+4)*4=272

// ---------------------------------------------------------------------------
// Kernel 1: extract (hash, sign) from both dense sketch matrices.
// blockIdx.x in [0,1024): rows 0..511 -> S1, 512..1023 -> S2.
// ---------------------------------------------------------------------------
__global__ __launch_bounds__(256) void extract_both(
    const float* __restrict__ S1, const float* __restrict__ S2,
    int* __restrict__ h, float* __restrict__ s) {
    const int row   = blockIdx.x & (C_DIM - 1);
    const int which = blockIdx.x >> 9;
    const float* S  = which ? S2 : S1;
    const float4* rowp = (const float4*)(S + (size_t)row * D_DIM);
    int*   hp = h + which * C_DIM;
    float* sp = s + which * C_DIM;
    for (int j4 = threadIdx.x; j4 < D_DIM / 4; j4 += 256) {
        float4 v = rowp[j4];
        if (v.x != 0.0f) { hp[row] = 4 * j4 + 0; sp[row] = v.x; }
        if (v.y != 0.0f) { hp[row] = 4 * j4 + 1; sp[row] = v.y; }
        if (v.z != 0.0f) { hp[row] = 4 * j4 + 2; sp[row] = v.z; }
        if (v.w != 0.0f) { hp[row] = 4 * j4 + 3; sp[row] = v.w; }
    }
}

// ---------------------------------------------------------------------------
// Kernel 2: 128x64 Gram tile (G = A*A^T slice, K=196) + LDS-histogram
// scatter + direct coalesced global-atomic flush to out.
// Grid: (8 j-tiles, 4 i-tiles, 16 batches) = 512 blocks.
// LDS: 32000 (hist) + 28*132*4 (At) + 28*68*4 (Bt) = 54400 B -> 2 blocks/CU.
// ---------------------------------------------------------------------------
__global__ __launch_bounds__(256, 2) void gram_hist(
    const float* __restrict__ x,     // [B, C, HW]
    const int* __restrict__ h1, const float* __restrict__ s1,
    const int* __restrict__ h2, const float* __restrict__ s2,
    float* __restrict__ out) {       // [B, D] (pre-zeroed)
    const int b  = blockIdx.z;
    const int i0 = blockIdx.y * IT;
    const int j0 = blockIdx.x * JT;
    const float* A = x + (size_t)b * C_DIM * HW_DIM;

    __shared__ float hist[D_DIM];
    __shared__ float At[KT][IT + PAD];   // K-major: fragment reads are float4
    __shared__ float Bt[KT][JT + PAD];

    const int tid = threadIdx.x;
    const int tx  = tid & 15;            // j: 16 * 4 = 64
    const int ty  = tid >> 4;            // i: 16 * 8 = 128

    for (int d = tid; d < D_DIM; d += 256) hist[d] = 0.0f;

    float acc[8][4] = {};

    for (int k0 = 0; k0 < HW_DIM; k0 += KT) {
        // A-tile: 128x28 = 3584 elems, 14/thread; B-tile: 64x28 = 1792, 7/thread.
        // Consecutive tid -> consecutive k: coalesced global reads.
        #pragma unroll
        for (int l = 0; l < 14; ++l) {
            int idx = l * 256 + tid;
            int r   = idx / KT;
            int kk  = idx - r * KT;
            At[kk][r] = A[(size_t)(i0 + r) * HW_DIM + k0 + kk];
        }
        #pragma unroll
        for (int l = 0; l < 7; ++l) {
            int idx = l * 256 + tid;
            int r   = idx / KT;
            int kk  = idx - r * KT;
            Bt[kk][r] = A[(size_t)(j0 + r) * HW_DIM + k0 + kk];
        }
        __syncthreads();

        #pragma unroll
        for (int kk = 0; kk < KT; ++kk) {
            float4 a0 = *(const float4*)&At[kk][ty * 8];
            float4 a1 = *(const float4*)&At[kk][ty * 8 + 4];
            float4 b0 = *(const float4*)&Bt[kk][tx * 4];
            float a[8]  = {a0.x, a0.y, a0.z, a0.w, a1.x, a1.y, a1.z, a1.w};
            float bb[4] = {b0.x, b0.y, b0.z, b0.w};
            #pragma unroll
            for (int u = 0; u < 8; ++u)
                #pragma unroll
                for (int v = 0; v < 4; ++v)
                    acc[u][v] += a[u] * bb[v];
        }
        __syncthreads();
    }

    // Scatter into the block-private LDS histogram (LDS atomics only).
    int hr[8]; float sr[8]; int hc[4]; float sc[4];
    #pragma unroll
    for (int u = 0; u < 8; ++u) {
        hr[u] = h1[i0 + ty * 8 + u];
        sr[u] = s1[i0 + ty * 8 + u];
    }
    #pragma unroll
    for (int v = 0; v < 4; ++v) {
        hc[v] = h2[j0 + tx * 4 + v];
        sc[v] = s2[j0 + tx * 4 + v];
    }
    #pragma unroll
    for (int u = 0; u < 8; ++u)
        #pragma unroll
        for (int v = 0; v < 4; ++v) {
            int bin = hr[u] + hc[v];
            if (bin >= D_DIM) bin -= D_DIM;
            atomicAdd(&hist[bin], sr[u] * sc[v] * acc[u][v]);
        }
    __syncthreads();

    // Flush: coalesced global atomics (consecutive lanes -> consecutive
    // addresses -> few cachelines per wave op), skipping empty bins.
    float* outb = out + (size_t)b * D_DIM;
    for (int d = tid; d < D_DIM; d += 256) {
        float v = hist[d];
        if (v != 0.0f) atomicAdd(outb + d, v);
    }
}

extern "C" void kernel_launch(void* const* d_in, const int* in_sizes, int n_in,
                              void* d_out, int out_size, void* d_ws, size_t ws_size,
                              hipStream_t stream) {
    const float* x  = (const float*)d_in[0];  // [16, 512, 14, 14] fp32
    const float* S1 = (const float*)d_in[1];  // [512, 8000] fp32
    const float* S2 = (const float*)d_in[2];  // [512, 8000] fp32
    float* out = (float*)d_out;               // [16, 8000] fp32

    // Workspace: h[1024] int | s[1024] f32  (8 KB total)
    int*   h = (int*)d_ws;
    float* s = (float*)(h + 2 * C_DIM);

    hipMemsetAsync(d_out, 0, (size_t)out_size * sizeof(float), stream);

    extract_both<<<2 * C_DIM, 256, 0, stream>>>(S1, S2, h, s);

    dim3 grid(C_DIM / JT, C_DIM / IT, B_DIM);   // (8, 4, 16) = 512 blocks
    gram_hist<<<grid, 256, 0, stream>>>(x, h, s, h + C_DIM, s + C_DIM, out);
}

// Round 4
// 122.403 us; speedup vs baseline: 1.1288x; 1.1288x over previous
//
#include <hip/hip_runtime.h>

// Problem constants: B=16, C=512, H=W=14 (HW=196), D=8000.
#define B_DIM 16
#define C_DIM 512
#define HW_DIM 196
#define D_DIM 8000
#define KP 224                      // K padded to 7*32 for MFMA 16x16x32
#define NROW (B_DIM * C_DIM)        // 8192 rows in xp

typedef __attribute__((ext_vector_type(8))) short short8;   // 8 bf16 frag
typedef __attribute__((ext_vector_type(4))) float float4v;  // 4 f32 acc

// ---------------------------------------------------------------------------
// Kernel 1 (prep): blocks 0..1023 extract (hash,sign) from S1/S2;
// blocks 1024..1535 convert x (fp32, K=196) -> xp (bf16, K padded to 224)
// and zero d_out. One dispatch, no memset needed.
// ---------------------------------------------------------------------------
__global__ __launch_bounds__(256) void prep(
    const float* __restrict__ x, const float* __restrict__ S1,
    const float* __restrict__ S2,
    int* __restrict__ h, float* __restrict__ s,
    unsigned short* __restrict__ xp, float* __restrict__ out) {
    const int bid = blockIdx.x;
    const int tid = threadIdx.x;
    if (bid < 2 * C_DIM) {
        const int row   = bid & (C_DIM - 1);
        const int which = bid >> 9;
        const float4* rowp = (const float4*)((which ? S2 : S1) + (size_t)row * D_DIM);
        int*   hp = h + which * C_DIM;
        float* sp = s + which * C_DIM;
        for (int j4 = tid; j4 < D_DIM / 4; j4 += 256) {
            float4 v = rowp[j4];
            if (v.x != 0.0f) { hp[row] = 4 * j4 + 0; sp[row] = v.x; }
            if (v.y != 0.0f) { hp[row] = 4 * j4 + 1; sp[row] = v.y; }
            if (v.z != 0.0f) { hp[row] = 4 * j4 + 2; sp[row] = v.z; }
            if (v.w != 0.0f) { hp[row] = 4 * j4 + 3; sp[row] = v.w; }
        }
    } else {
        const int j = bid - 2 * C_DIM;        // 0..511, 16 rows each
        #pragma unroll
        for (int l = 0; l < 14; ++l) {        // 14*256 = 3584 = 16*224
            int idx = l * 256 + tid;
            int r   = idx / KP;
            int kk  = idx - r * KP;
            int row = j * 16 + r;
            float v = (kk < HW_DIM) ? x[(size_t)row * HW_DIM + kk] : 0.0f;
            unsigned int u = __float_as_uint(v);          // RNE fp32 -> bf16
            u = (u + 0x7FFFu + ((u >> 16) & 1u)) >> 16;
            xp[(size_t)row * KP + kk] = (unsigned short)u;
        }
        if (j < 500) out[j * 256 + tid] = 0.0f;           // 500*256 = 128000
    }
}

// ---------------------------------------------------------------------------
// Kernel 2: barrier-free MFMA Gram + LDS-histogram scatter.
// Block = 4 waves; block tile 128(i) x 64(j); wave tile 32x64 = 2x4 MFMA
// tiles of 16x16. Fragments loaded directly from global bf16 (no LDS
// staging, no K-loop barriers). LDS = 32 KB histogram only.
// Grid: (8 j, 4 i, 16 b) = 512 blocks.
// ---------------------------------------------------------------------------
__global__ __launch_bounds__(256) void gram_hist(
    const unsigned short* __restrict__ xp,   // [B*C, KP] bf16 bits
    const int* __restrict__ h1, const float* __restrict__ s1,
    const int* __restrict__ h2, const float* __restrict__ s2,
    float* __restrict__ out) {               // [B, D]
    const int b  = blockIdx.z;
    const int i0 = blockIdx.y * 128;
    const int j0 = blockIdx.x * 64;

    __shared__ float hist[D_DIM];
    const int tid = threadIdx.x;
    for (int d = tid; d < D_DIM; d += 256) hist[d] = 0.0f;
    __syncthreads();

    const int w  = tid >> 6;    // wave 0..3 -> i rows [i0+32w, +32)
    const int l  = tid & 63;
    const int rA = l & 15;      // fragment row within 16x16 tile
    const int g  = l >> 4;      // k-group: 8 contiguous k at g*8

    const unsigned short* base = xp + (size_t)b * C_DIM * KP;
    const unsigned short* pA[2];
    const unsigned short* pB[4];
    #pragma unroll
    for (int mt = 0; mt < 2; ++mt)
        pA[mt] = base + (size_t)(i0 + w * 32 + mt * 16 + rA) * KP + g * 8;
    #pragma unroll
    for (int nt = 0; nt < 4; ++nt)
        pB[nt] = base + (size_t)(j0 + nt * 16 + rA) * KP + g * 8;

    float4v acc[2][4];
    #pragma unroll
    for (int mt = 0; mt < 2; ++mt)
        #pragma unroll
        for (int nt = 0; nt < 4; ++nt)
            acc[mt][nt] = (float4v){0.0f, 0.0f, 0.0f, 0.0f};

    short8 fa[2], fb[4];
    #pragma unroll
    for (int mt = 0; mt < 2; ++mt) fa[mt] = *(const short8*)pA[mt];
    #pragma unroll
    for (int nt = 0; nt < 4; ++nt) fb[nt] = *(const short8*)pB[nt];

    // 7 K-steps of 32; register double-buffered prefetch; zero barriers.
    #pragma unroll
    for (int step = 1; step <= 7; ++step) {
        short8 na[2], nb[4];
        if (step < 7) {
            #pragma unroll
            for (int mt = 0; mt < 2; ++mt) na[mt] = *(const short8*)(pA[mt] + step * 32);
            #pragma unroll
            for (int nt = 0; nt < 4; ++nt) nb[nt] = *(const short8*)(pB[nt] + step * 32);
        }
        #pragma unroll
        for (int mt = 0; mt < 2; ++mt)
            #pragma unroll
            for (int nt = 0; nt < 4; ++nt)
                acc[mt][nt] = __builtin_amdgcn_mfma_f32_16x16x32_bf16(
                    fa[mt], fb[nt], acc[mt][nt], 0, 0, 0);
        if (step < 7) {
            #pragma unroll
            for (int mt = 0; mt < 2; ++mt) fa[mt] = na[mt];
            #pragma unroll
            for (int nt = 0; nt < 4; ++nt) fb[nt] = nb[nt];
        }
    }

    // Scatter: C/D layout col = lane&15, row = (lane>>4)*4 + reg (verified).
    int hr[2][4]; float sr[2][4]; int hc[4]; float sc[4];
    #pragma unroll
    for (int mt = 0; mt < 2; ++mt)
        #pragma unroll
        for (int r = 0; r < 4; ++r) {
            int c1 = i0 + w * 32 + mt * 16 + (l >> 4) * 4 + r;
            hr[mt][r] = h1[c1]; sr[mt][r] = s1[c1];
        }
    #pragma unroll
    for (int nt = 0; nt < 4; ++nt) {
        int c2 = j0 + nt * 16 + (l & 15);
        hc[nt] = h2[c2]; sc[nt] = s2[c2];
    }
    #pragma unroll
    for (int mt = 0; mt < 2; ++mt)
        #pragma unroll
        for (int nt = 0; nt < 4; ++nt)
            #pragma unroll
            for (int r = 0; r < 4; ++r) {
                int bin = hr[mt][r] + hc[nt];
                if (bin >= D_DIM) bin -= D_DIM;
                atomicAdd(&hist[bin], sr[mt][r] * sc[nt] * acc[mt][nt][r]);
            }
    __syncthreads();

    // Coalesced global-atomic flush, skipping empty bins.
    float* outb = out + (size_t)b * D_DIM;
    for (int d = tid; d < D_DIM; d += 256) {
        float v = hist[d];
        if (v != 0.0f) atomicAdd(outb + d, v);
    }
}

extern "C" void kernel_launch(void* const* d_in, const int* in_sizes, int n_in,
                              void* d_out, int out_size, void* d_ws, size_t ws_size,
                              hipStream_t stream) {
    const float* x  = (const float*)d_in[0];  // [16, 512, 14, 14] fp32
    const float* S1 = (const float*)d_in[1];  // [512, 8000] fp32
    const float* S2 = (const float*)d_in[2];  // [512, 8000] fp32
    float* out = (float*)d_out;               // [16, 8000] fp32

    // ws: h[1024] int | s[1024] f32 | xp[8192*224] bf16 (~3.7 MB)
    int*            h  = (int*)d_ws;
    float*          s  = (float*)(h + 2 * C_DIM);
    unsigned short* xp = (unsigned short*)(s + 2 * C_DIM);

    prep<<<2 * C_DIM + NROW / 16, 256, 0, stream>>>(x, S1, S2, h, s, xp, out);

    dim3 grid(C_DIM / 64, C_DIM / 128, B_DIM);   // (8, 4, 16) = 512 blocks
    gram_hist<<<grid, 256, 0, stream>>>(xp, h, s, h + C_DIM, s + C_DIM, out);
}

// Round 5
// 117.534 us; speedup vs baseline: 1.1756x; 1.0414x over previous
//
#include <hip/hip_runtime.h>

// Problem constants: B=16, C=512, H=W=14 (HW=196), D=8000.
#define B_DIM 16
#define C_DIM 512
#define HW_DIM 196
#define D_DIM 8000
#define KP 224                      // K padded to 7*32 for MFMA 16x16x32
#define NROW (B_DIM * C_DIM)        // 8192 rows in xp
#define NBLK 512                    // gram blocks = 8j * 4i * 16b

typedef __attribute__((ext_vector_type(8))) short short8;   // 8 bf16 frag
typedef __attribute__((ext_vector_type(4))) float float4v;  // 4 f32 acc

// ---------------------------------------------------------------------------
// Kernel 1 (prep): blocks 0..1023 extract (hash,sign) from S1/S2;
// blocks 1024..1535 convert x (fp32, K=196) -> xp (bf16, K padded to 224).
// ---------------------------------------------------------------------------
__global__ __launch_bounds__(256) void prep(
    const float* __restrict__ x, const float* __restrict__ S1,
    const float* __restrict__ S2,
    int* __restrict__ h, float* __restrict__ s,
    unsigned short* __restrict__ xp) {
    const int bid = blockIdx.x;
    const int tid = threadIdx.x;
    if (bid < 2 * C_DIM) {
        const int row   = bid & (C_DIM - 1);
        const int which = bid >> 9;
        const float4* rowp = (const float4*)((which ? S2 : S1) + (size_t)row * D_DIM);
        int*   hp = h + which * C_DIM;
        float* sp = s + which * C_DIM;
        for (int j4 = tid; j4 < D_DIM / 4; j4 += 256) {
            float4 v = rowp[j4];
            if (v.x != 0.0f) { hp[row] = 4 * j4 + 0; sp[row] = v.x; }
            if (v.y != 0.0f) { hp[row] = 4 * j4 + 1; sp[row] = v.y; }
            if (v.z != 0.0f) { hp[row] = 4 * j4 + 2; sp[row] = v.z; }
            if (v.w != 0.0f) { hp[row] = 4 * j4 + 3; sp[row] = v.w; }
        }
    } else {
        const int j = bid - 2 * C_DIM;        // 0..511, 16 rows each
        #pragma unroll
        for (int l = 0; l < 14; ++l) {        // 14*256 = 3584 = 16*224
            int idx = l * 256 + tid;
            int r   = idx / KP;
            int kk  = idx - r * KP;
            int row = j * 16 + r;
            float v = (kk < HW_DIM) ? x[(size_t)row * HW_DIM + kk] : 0.0f;
            unsigned int u = __float_as_uint(v);          // RNE fp32 -> bf16
            u = (u + 0x7FFFu + ((u >> 16) & 1u)) >> 16;
            xp[(size_t)row * KP + kk] = (unsigned short)u;
        }
    }
}

// ---------------------------------------------------------------------------
// Kernel 2: barrier-free MFMA Gram + LDS-histogram scatter + plain coalesced
// float4 flush to a per-block partial histogram (no global atomics at all).
// Block = 4 waves; block tile 128(i) x 64(j); wave tile 32x64 = 2x4 MFMA
// tiles of 16x16, fragments loaded directly from global bf16.
// Grid: (8 j, 4 i, 16 b) = 512 blocks. LDS = 32 KB histogram only.
// ---------------------------------------------------------------------------
__global__ __launch_bounds__(256) void gram_hist(
    const unsigned short* __restrict__ xp,   // [B*C, KP] bf16 bits
    const int* __restrict__ h1, const float* __restrict__ s1,
    const int* __restrict__ h2, const float* __restrict__ s2,
    float* __restrict__ part) {              // [512, D] partials
    const int b  = blockIdx.z;
    const int i0 = blockIdx.y * 128;
    const int j0 = blockIdx.x * 64;

    __shared__ __align__(16) float hist[D_DIM];
    const int tid = threadIdx.x;
    #pragma unroll
    for (int l = 0; l < D_DIM / 1024; ++l)               // 2000 float4 / 256
        ((float4*)hist)[l * 256 + tid] = (float4){0.f, 0.f, 0.f, 0.f};
    if (tid < D_DIM / 4 - (D_DIM / 1024) * 256)
        ((float4*)hist)[(D_DIM / 1024) * 256 + tid] = (float4){0.f, 0.f, 0.f, 0.f};
    __syncthreads();

    const int w  = tid >> 6;    // wave 0..3 -> i rows [i0+32w, +32)
    const int l  = tid & 63;
    const int rA = l & 15;      // fragment row within 16x16 tile
    const int g  = l >> 4;      // k-group: 8 contiguous k at g*8

    const unsigned short* base = xp + (size_t)b * C_DIM * KP;
    const unsigned short* pA[2];
    const unsigned short* pB[4];
    #pragma unroll
    for (int mt = 0; mt < 2; ++mt)
        pA[mt] = base + (size_t)(i0 + w * 32 + mt * 16 + rA) * KP + g * 8;
    #pragma unroll
    for (int nt = 0; nt < 4; ++nt)
        pB[nt] = base + (size_t)(j0 + nt * 16 + rA) * KP + g * 8;

    float4v acc[2][4];
    #pragma unroll
    for (int mt = 0; mt < 2; ++mt)
        #pragma unroll
        for (int nt = 0; nt < 4; ++nt)
            acc[mt][nt] = (float4v){0.0f, 0.0f, 0.0f, 0.0f};

    short8 fa[2], fb[4];
    #pragma unroll
    for (int mt = 0; mt < 2; ++mt) fa[mt] = *(const short8*)pA[mt];
    #pragma unroll
    for (int nt = 0; nt < 4; ++nt) fb[nt] = *(const short8*)pB[nt];

    // 7 K-steps of 32; register double-buffered prefetch; zero barriers.
    #pragma unroll
    for (int step = 1; step <= 7; ++step) {
        short8 na[2], nb[4];
        if (step < 7) {
            #pragma unroll
            for (int mt = 0; mt < 2; ++mt) na[mt] = *(const short8*)(pA[mt] + step * 32);
            #pragma unroll
            for (int nt = 0; nt < 4; ++nt) nb[nt] = *(const short8*)(pB[nt] + step * 32);
        }
        #pragma unroll
        for (int mt = 0; mt < 2; ++mt)
            #pragma unroll
            for (int nt = 0; nt < 4; ++nt)
                acc[mt][nt] = __builtin_amdgcn_mfma_f32_16x16x32_bf16(
                    fa[mt], fb[nt], acc[mt][nt], 0, 0, 0);
        if (step < 7) {
            #pragma unroll
            for (int mt = 0; mt < 2; ++mt) fa[mt] = na[mt];
            #pragma unroll
            for (int nt = 0; nt < 4; ++nt) fb[nt] = nb[nt];
        }
    }

    // Scatter: C/D layout col = lane&15, row = (lane>>4)*4 + reg (verified).
    int hr[2][4]; float sr[2][4]; int hc[4]; float sc[4];
    #pragma unroll
    for (int mt = 0; mt < 2; ++mt)
        #pragma unroll
        for (int r = 0; r < 4; ++r) {
            int c1 = i0 + w * 32 + mt * 16 + (l >> 4) * 4 + r;
            hr[mt][r] = h1[c1]; sr[mt][r] = s1[c1];
        }
    #pragma unroll
    for (int nt = 0; nt < 4; ++nt) {
        int c2 = j0 + nt * 16 + (l & 15);
        hc[nt] = h2[c2]; sc[nt] = s2[c2];
    }
    #pragma unroll
    for (int mt = 0; mt < 2; ++mt)
        #pragma unroll
        for (int nt = 0; nt < 4; ++nt)
            #pragma unroll
            for (int r = 0; r < 4; ++r) {
                int bin = hr[mt][r] + hc[nt];
                if (bin >= D_DIM) bin -= D_DIM;
                atomicAdd(&hist[bin], sr[mt][r] * sc[nt] * acc[mt][nt][r]);
            }
    __syncthreads();

    // Flush: plain coalesced float4 stores to this block's private slice.
    float* pb = part + (size_t)(((size_t)b * 4 + blockIdx.y) * 8 + blockIdx.x) * D_DIM;
    #pragma unroll
    for (int l4 = 0; l4 < D_DIM / 1024; ++l4)
        ((float4*)pb)[l4 * 256 + tid] = ((const float4*)hist)[l4 * 256 + tid];
    if (tid < D_DIM / 4 - (D_DIM / 1024) * 256)
        ((float4*)pb)[(D_DIM / 1024) * 256 + tid] =
            ((const float4*)hist)[(D_DIM / 1024) * 256 + tid];
}

// ---------------------------------------------------------------------------
// Kernel 3: reduce the 32 partials of each batch -> out[b, d]. Plain stores;
// fully overwrites out (no memset needed).
// ---------------------------------------------------------------------------
__global__ __launch_bounds__(256) void reduce_part(
    const float* __restrict__ part, float* __restrict__ out) {
    int idx = blockIdx.x * 256 + threadIdx.x;   // over B*D = 128000
    if (idx >= B_DIM * D_DIM) return;
    int b = idx / D_DIM;
    int d = idx - b * D_DIM;
    const float* p = part + (size_t)b * 32 * D_DIM + d;
    float v = 0.0f;
    #pragma unroll
    for (int t = 0; t < 32; ++t) v += p[(size_t)t * D_DIM];
    out[idx] = v;
}

extern "C" void kernel_launch(void* const* d_in, const int* in_sizes, int n_in,
                              void* d_out, int out_size, void* d_ws, size_t ws_size,
                              hipStream_t stream) {
    const float* x  = (const float*)d_in[0];  // [16, 512, 14, 14] fp32
    const float* S1 = (const float*)d_in[1];  // [512, 8000] fp32
    const float* S2 = (const float*)d_in[2];  // [512, 8000] fp32
    float* out = (float*)d_out;               // [16, 8000] fp32

    // ws: h[1024] int | s[1024] f32 | xp[8192*224] bf16 (3.7 MB)
    //   | part[512*8000] f32 (16.4 MB)
    int*            h    = (int*)d_ws;
    float*          s    = (float*)(h + 2 * C_DIM);
    unsigned short* xp   = (unsigned short*)(s + 2 * C_DIM);
    float*          part = (float*)(xp + (size_t)NROW * KP);

    prep<<<2 * C_DIM + NROW / 16, 256, 0, stream>>>(x, S1, S2, h, s, xp);

    dim3 grid(C_DIM / 64, C_DIM / 128, B_DIM);   // (8, 4, 16) = 512 blocks
    gram_hist<<<grid, 256, 0, stream>>>(xp, h, s, h + C_DIM, s + C_DIM, part);

    reduce_part<<<(B_DIM * D_DIM + 255) / 256, 256, 0, stream>>>(part, out);
}